// Round 13
// baseline (55.125 us; speedup 1.0000x reference)
//
#include <hip/hip_runtime.h>
#include <hip/hip_bf16.h>
#include <cstdint>

// Problem constants
#define BATCH 16
#define HDIM 768
#define WDIM 768
#define HW (HDIM * WDIM)              // 589824
#define NPIX (BATCH * HW)             // 9437184
#define MAX_DET 393216
#define NWORDS (NPIX / 64)            // 147456

// mask tile geometry (r8's proven 32x256)
#define TILE_C 256
#define TILE_R 32
#define LDS_C 264                     // cols cs*256-4 .. cs*256+259
#define LDS_R 36                      // rows r0-2 .. r0+33
#define VEC_PER_ROW 66                // 264/4
#define TOT_VEC (LDS_R * VEC_PER_ROW) // 2376

// scatter chunking: 384 flat-contiguous words per chunk == one (b,rt) row-tile
#define NCHUNKS 384                   // NWORDS / 384

// ws layout (byte offsets)
#define WORD_OFF 0u                   // NWORDS * 8 = 1179648
#define CNT_OFF  1179648u             // NCHUNKS * 4 = 1536
#define TOT_OFF  1181184u             // 4
#define IDX_OFF  1183744u             // MAX_DET * 4

// Output layout (float elements)
#define SIGMA_BASE 0
#define POS_BASE   786432
#define HGT_BASE   1572864
#define GOOD_BASE  2359296

// ---------------------------------------------------------------
// ln(zf), f32: exact exponent split + hw v_log_f32 on mantissa.
// ---------------------------------------------------------------
__device__ __forceinline__ float fast_logf(float zf) {
    int ib = __float_as_int(zf);
    int e = ((ib >> 23) & 255) - 127;
    float m1 = __int_as_float((ib & 0x007fffff) | 0x3f800000);  // [1,2)
    float lg = __builtin_amdgcn_logf(m1);                       // log2(m1)
    return ((float)e + lg) * 0.69314718055994531f;
}

// Reciprocal via HW rcp_f32 seed + 2 f64 Newtons.
__device__ __forceinline__ double fast_rcp(double d) {
    double r = (double)__builtin_amdgcn_rcpf((float)d);
    r = r * (2.0 - d * r);
    r = r * (2.0 - d * r);
    return r;
}

// ---------------------------------------------------------------
// Kernel 1: local-max mask (separable 5x5, LDS-tiled) + per-chunk
// count via ONE atomicAdd per block. Block (b,rt,cs) covers flat
// words b*9216 + rt*384 + (k*12 + cs*4 + wi): the 3 cs-blocks of a
// row-tile exactly tile chunk = b*24+rt (384 contiguous words).
// ---------------------------------------------------------------
__global__ __launch_bounds__(256) void mask_kernel(const float* __restrict__ x,
                                                   unsigned long long* __restrict__ words,
                                                   int* __restrict__ counts) {
    __shared__ float lds[LDS_R * LDS_C];
    const int bid = blockIdx.x;             // 16 * 24 * 3 = 1152 blocks
    const int b   = bid / 72;
    const int rem = bid - b * 72;
    const int rt  = rem / 3;                // row tile 0..23
    const int cs  = rem - rt * 3;           // col strip 0..2
    const int r0  = rt * TILE_R;
    const int tid = threadIdx.x;
    const float* heat = x + (size_t)b * (2 * HW) + HW;   // channel 1

    // ---- stage thresholded tile (+halo) into LDS ----
    const int colbase = cs * TILE_C - 4;
    #pragma unroll
    for (int i = 0; i < 10; ++i) {
        int idx = i * 256 + tid;
        if (idx < TOT_VEC) {
            int lr = (unsigned)idx / VEC_PER_ROW;
            int q  = idx - lr * VEC_PER_ROW;
            int row = r0 - 2 + lr;
            int col = colbase + 4 * q;      // fully in-image or fully out
            float4 v = make_float4(0.f, 0.f, 0.f, 0.f);
            if (row >= 0 && row < HDIM && col >= 0 && col <= WDIM - 4) {
                v = *reinterpret_cast<const float4*>(heat + (size_t)row * WDIM + col);
            }
            float4 t;
            t.x = v.x > 0.5f ? v.x : 0.f;
            t.y = v.y > 0.5f ? v.y : 0.f;
            t.z = v.z > 0.5f ? v.z : 0.f;
            t.w = v.w > 0.5f ? v.w : 0.f;
            *reinterpret_cast<float4*>(&lds[lr * LDS_C + 4 * q]) = t;
        }
    }
    __syncthreads();

    // ---- compute: wave wv handles rows r0+wv*8 .. +7; lane owns 4 cols ----
    const int wv   = tid >> 6;
    const int lane = tid & 63;
    const int lrow0 = wv * 8;               // LDS row of first window row

    auto readrow = [&](int ldsrow, float* h5, float* hx, float* tc) {
        const float* p = &lds[ldsrow * LDS_C + 4 * lane];
        float4 a = *reinterpret_cast<const float4*>(p);
        float4 bb = *reinterpret_cast<const float4*>(p + 4);
        float4 cc = *reinterpret_cast<const float4*>(p + 8);
        float t2=a.z,t3=a.w,t4=bb.x,t5=bb.y,t6=bb.z,t7=bb.w,t8=cc.x,t9=cc.y;
        float pp0=fmaxf(t2,t3), pp1=fmaxf(t3,t4), pp2=fmaxf(t4,t5), pp3=fmaxf(t5,t6),
              pp4=fmaxf(t6,t7), pp5=fmaxf(t7,t8), pp6=fmaxf(t8,t9);
        h5[0]=fmaxf(fmaxf(pp0,pp2),t6);  hx[0]=fmaxf(pp0,pp3);  tc[0]=t4;
        h5[1]=fmaxf(fmaxf(pp1,pp3),t7);  hx[1]=fmaxf(pp1,pp4);  tc[1]=t5;
        h5[2]=fmaxf(fmaxf(pp2,pp4),t8);  hx[2]=fmaxf(pp2,pp5);  tc[2]=t6;
        h5[3]=fmaxf(fmaxf(pp3,pp5),t9);  hx[3]=fmaxf(pp3,pp6);  tc[3]=t7;
    };

    float h5r[5][4], hxr[5][4], tcr[5][4];
    #pragma unroll
    for (int j = 0; j < 4; ++j)
        readrow(lrow0 + j, h5r[j], hxr[j], tcr[j]);

    unsigned nibword = 0;                   // 8 nibbles, one per k
    #pragma unroll
    for (int k = 0; k < 8; ++k) {
        readrow(lrow0 + k + 4, h5r[(k+4)%5], hxr[(k+4)%5], tcr[(k+4)%5]);
        unsigned nib = 0;
        #pragma unroll
        for (int c = 0; c < 4; ++c) {
            float dil = fmaxf(fmaxf(h5r[k%5][c], h5r[(k+1)%5][c]),
                        fmaxf(hxr[(k+2)%5][c],
                        fmaxf(h5r[(k+3)%5][c], h5r[(k+4)%5][c])));
            if (tcr[(k+2)%5][c] > dil) nib |= (1u << c);
        }
        nibword |= nib << (4 * k);
    }

    // ---- word assembly via LDS round-trip (no shfl chains) ----
    __syncthreads();                        // all float reads done
    unsigned* lu = (unsigned*)lds;          // [0..255]
    int* su = (int*)lds + 512;              // [512..639]: popcount reduce
    lu[tid] = nibword;
    __syncthreads();

    int pc = 0;
    if (tid < 128) {
        const int wv2 = tid >> 5;           // 0..3 (wave group)
        const int k2  = (tid >> 2) & 7;     // 0..7 (row within group)
        const int wi  = tid & 3;            // 0..3 (word within row strip)
        const int s   = 4 * k2;
        const uint4* p = (const uint4*)&lu[wv2 * 64 + wi * 16];
        uint4 q0 = p[0], q1 = p[1], q2 = p[2], q3 = p[3];
        unsigned lo = 0, hi = 0;
        lo |= ((q0.x >> s) & 0xFu) << 0;   lo |= ((q0.y >> s) & 0xFu) << 4;
        lo |= ((q0.z >> s) & 0xFu) << 8;   lo |= ((q0.w >> s) & 0xFu) << 12;
        lo |= ((q1.x >> s) & 0xFu) << 16;  lo |= ((q1.y >> s) & 0xFu) << 20;
        lo |= ((q1.z >> s) & 0xFu) << 24;  lo |= ((q1.w >> s) & 0xFu) << 28;
        hi |= ((q2.x >> s) & 0xFu) << 0;   hi |= ((q2.y >> s) & 0xFu) << 4;
        hi |= ((q2.z >> s) & 0xFu) << 8;   hi |= ((q2.w >> s) & 0xFu) << 12;
        hi |= ((q3.x >> s) & 0xFu) << 16;  hi |= ((q3.y >> s) & 0xFu) << 20;
        hi |= ((q3.z >> s) & 0xFu) << 24;  hi |= ((q3.w >> s) & 0xFu) << 28;
        unsigned long long word = (unsigned long long)lo |
                                  ((unsigned long long)hi << 32);
        words[b * (HW / 64) + (r0 + wv2 * 8 + k2) * 12 + cs * 4 + wi] = word;
        pc = __popcll(word);
    }
    // block popcount reduce -> one atomicAdd into chunk counter
    if (tid < 128) su[tid] = pc;
    __syncthreads();
    #pragma unroll
    for (int off = 64; off > 0; off >>= 1) {
        if (tid < off) su[tid] += su[tid + off];
        __syncthreads();
    }
    if (tid == 0) atomicAdd(&counts[b * 24 + rt], su[0]);
}

// ---------------------------------------------------------------
// Kernel 2: ordered scatter over 384-word flat-contiguous chunks.
// blockoff = sum(counts[0..chunk)).
// ---------------------------------------------------------------
__global__ __launch_bounds__(384) void scatter_kernel(const unsigned long long* __restrict__ words,
                                                      const int* __restrict__ counts,
                                                      int* __restrict__ flat_idx,
                                                      int* __restrict__ total) {
    __shared__ int s[512];
    __shared__ int s2[384];
    __shared__ int blockoff;
    const int t = threadIdx.x;                // 0..383
    const int chunk = blockIdx.x;             // 0..383

    // exclusive prefix over chunks [0, chunk): each thread covers <=1 slot
    s[t] = (t < chunk) ? counts[t] : 0;
    if (t < 128) s[384 + t] = 0;
    __syncthreads();
    #pragma unroll
    for (int off = 256; off > 0; off >>= 1) {
        if (t < off) s[t] += s[t + off];
        __syncthreads();
    }
    if (t == 0) blockoff = s[0];
    __syncthreads();

    // load word, in-block inclusive scan of popcounts (Hillis-Steele)
    unsigned long long m = words[chunk * 384 + t];
    int pc = __popcll(m);
    s2[t] = pc;
    __syncthreads();
    for (int off = 1; off < 384; off <<= 1) {
        int add = (t >= off) ? s2[t - off] : 0;
        __syncthreads();
        s2[t] += add;
        __syncthreads();
    }
    if (chunk == NCHUNKS - 1 && t == 383)
        *total = blockoff + s2[383];

    int base = blockoff + s2[t] - pc;
    int idx0 = (chunk * 384 + t) << 6;
    while (m) {
        int j = __builtin_ctzll(m);
        if (base < MAX_DET) flat_idx[base] = idx0 + j;
        ++base;
        m &= m - 1;
    }
}

// ---------------------------------------------------------------
// Kernel 3: fit — float4-pair gather -> f32 moments -> f64 GE.
// ---------------------------------------------------------------
__global__ __launch_bounds__(256) void fit_kernel(const float* __restrict__ x,
                                                  const int* __restrict__ flat_idx,
                                                  const int* __restrict__ total,
                                                  float* __restrict__ out) {
    int n = blockIdx.x * 256 + threadIdx.x;   // 0..MAX_DET-1 (grid exact)
    int count = min(*total, MAX_DET);
    float sx = 0.f, sy = 0.f, p0 = 0.f, p1 = 0.f, h0 = 0.f, h1 = 0.f, goodf = 0.f;
    if (n < count) {
        int idx = flat_idx[n];
        int b = idx / HW;
        int rc = idx - b * HW;
        int r = rc / WDIM;
        int c = rc - r * WDIM;
        const float* heat = x + (size_t)b * (2 * HW) + HW;

        // gather 5x5 neighborhood (clipped) into registers
        float zv[25];
        if (c >= 2 && c <= WDIM - 3) {
            // fast path: 2 aligned float4 loads per row cover cols c-2..c+2
            const int a   = (c - 2) & ~3;
            const int ofs = (c - 2) & 3;
            #pragma unroll
            for (int dy = 0; dy < 5; ++dy) {
                int rr = min(max(r + dy - 2, 0), HDIM - 1);
                const float* hp = heat + (size_t)rr * WDIM + a;
                float4 u0 = *reinterpret_cast<const float4*>(hp);
                float4 u1 = *reinterpret_cast<const float4*>(hp + 4);
                float b0=u0.x, b1=u0.y, b2=u0.z, b3=u0.w;
                float b4=u1.x, b5=u1.y, b6=u1.z, b7=u1.w;
                float v0, v1, v2, v3, v4;
                if (ofs == 0)      { v0=b0; v1=b1; v2=b2; v3=b3; v4=b4; }
                else if (ofs == 1) { v0=b1; v1=b2; v2=b3; v3=b4; v4=b5; }
                else if (ofs == 2) { v0=b2; v1=b3; v2=b4; v3=b5; v4=b6; }
                else               { v0=b3; v1=b4; v2=b5; v3=b6; v4=b7; }
                zv[dy*5+0]=v0; zv[dy*5+1]=v1; zv[dy*5+2]=v2; zv[dy*5+3]=v3; zv[dy*5+4]=v4;
            }
        } else {
            #pragma unroll
            for (int dy = 0; dy < 5; ++dy) {
                int rr = min(max(r + dy - 2, 0), HDIM - 1);
                const float* hp = heat + (size_t)rr * WDIM;
                #pragma unroll
                for (int dx = 0; dx < 5; ++dx) {
                    int cc = min(max(c + dx - 2, 0), WDIM - 1);
                    zv[dy * 5 + dx] = hp[cc];
                }
            }
        }

        // Row-factorized moments in f32, weight w2 = z^4
        float M00=0,M10=0,M01=0,M20=0,M11=0,M02=0,M30=0,M21=0,M12=0,M03=0;
        float M40=0,M31=0,M22=0,M13=0,M04=0;
        float N0=0,N1=0,N2=0,N3=0,N4=0,N5=0;
        #pragma unroll
        for (int dy = -2; dy <= 2; ++dy) {
            float S0=0,S1=0,S2=0,S3=0,S4=0,T0=0,T1=0,T2=0;
            #pragma unroll
            for (int dx = -2; dx <= 2; ++dx) {
                float zf = fmaxf(zv[(dy + 2) * 5 + dx + 2], 1e-6f);
                float z2 = zf * zf;
                float w2 = z2 * z2;
                float wl = w2 * fast_logf(zf);
                const float X = (float)dx;         // literal after unroll
                S0 += w2; T0 += wl;
                if (dx != 0) {
                    S1 += w2 * X;
                    S2 += w2 * (X * X);
                    S3 += w2 * (X * X * X);
                    S4 += w2 * (X * X * X * X);
                    T1 += wl * X;
                    T2 += wl * (X * X);
                }
            }
            const float Y = (float)dy;             // literal after unroll
            M00 += S0; M10 += S1; M20 += S2; M30 += S3; M40 += S4;
            N0 += T0; N1 += T1; N2 += T2;
            if (dy != 0) {
                float Y2 = Y * Y, Y3 = Y2 * Y, Y4 = Y2 * Y2;
                M01 += S0 * Y;  M11 += S1 * Y;  M21 += S2 * Y;  M31 += S3 * Y;
                M02 += S0 * Y2; M12 += S1 * Y2; M22 += S2 * Y2;
                M03 += S0 * Y3; M13 += S1 * Y3;
                M04 += S0 * Y4;
                N3 += T0 * Y; N4 += T1 * Y; N5 += T0 * Y2;
            }
        }

        // Augmented 6x7 normal equations (f64), basis [1, x, x2, y, xy, y2]
        double A[6][7];
        A[0][0]=M00; A[0][1]=M10; A[0][2]=M20; A[0][3]=M01; A[0][4]=M11; A[0][5]=M02; A[0][6]=N0;
        A[1][0]=M10; A[1][1]=M20; A[1][2]=M30; A[1][3]=M11; A[1][4]=M21; A[1][5]=M12; A[1][6]=N1;
        A[2][0]=M20; A[2][1]=M30; A[2][2]=M40; A[2][3]=M21; A[2][4]=M31; A[2][5]=M22; A[2][6]=N2;
        A[3][0]=M01; A[3][1]=M11; A[3][2]=M21; A[3][3]=M02; A[3][4]=M12; A[3][5]=M03; A[3][6]=N3;
        A[4][0]=M11; A[4][1]=M21; A[4][2]=M31; A[4][3]=M12; A[4][4]=M22; A[4][5]=M13; A[4][6]=N4;
        A[5][0]=M02; A[5][1]=M12; A[5][2]=M22; A[5][3]=M03; A[5][4]=M13; A[5][5]=M04; A[5][6]=N5;

        // Gaussian elimination (no pivot; SPD), fully unrolled -> registers
        #pragma unroll
        for (int i = 0; i < 6; ++i) {
            double inv = fast_rcp(A[i][i]);
            #pragma unroll
            for (int j = i + 1; j < 7; ++j) A[i][j] *= inv;
            #pragma unroll
            for (int ii = i + 1; ii < 6; ++ii) {
                double f = A[ii][i];
                #pragma unroll
                for (int j = i + 1; j < 7; ++j) A[ii][j] -= f * A[i][j];
            }
        }
        double cv[6];
        #pragma unroll
        for (int i = 5; i >= 0; --i) {
            double v = A[i][6];
            #pragma unroll
            for (int j = i + 1; j < 6; ++j) v -= A[i][j] * cv[j];
            cv[i] = v;
        }

        double aqx = cv[2], aqy = cv[5];
        if (aqx < 0.0 && aqy < 0.0) {
            double sx2 = -0.5 * fast_rcp(aqx);
            double sy2 = -0.5 * fast_rcp(aqy);
            sx2 = fmin(sx2, 1e300);
            sy2 = fmin(sy2, 1e300);
            double sigx = sqrt(sx2), sigy = sqrt(sy2);
            double mux = cv[1] * sx2, muy = cv[3] * sy2;
            sx = (float)sigx;
            sy = (float)sigy;
            p0 = (float)((double)r + muy);   // pos[:,0] = r + mu_y
            p1 = (float)((double)c + mux);   // pos[:,1] = c + mu_x
            // height threshold is inf (observed): f32 exp2 path, clamped finite.
            float a0 = (float)((cv[0] + 0.5 * cv[1] * cv[1] * sx2) * 1.4426950408889634);
            float a1 = (float)((cv[4] + 0.5 * cv[3] * cv[3] * sy2) * 1.4426950408889634);
            a0 = fminf(a0, 126.0f);          // exp2(126)=8.5e37: finite in f32
            a1 = fminf(a1, 126.0f);
            h0 = exp2f(a0);
            h1 = exp2f(a1);
            goodf = 1.0f;
        }
    }
    out[SIGMA_BASE + 2 * n]     = sx;
    out[SIGMA_BASE + 2 * n + 1] = sy;
    out[POS_BASE + 2 * n]       = p0;
    out[POS_BASE + 2 * n + 1]   = p1;
    out[HGT_BASE + 2 * n]       = h0;
    out[HGT_BASE + 2 * n + 1]   = h1;
    out[GOOD_BASE + n]          = goodf;
}

extern "C" void kernel_launch(void* const* d_in, const int* in_sizes, int n_in,
                              void* d_out, int out_size, void* d_ws, size_t ws_size,
                              hipStream_t stream) {
    const float* x = (const float*)d_in[0];
    float* out = (float*)d_out;
    char* ws = (char*)d_ws;

    unsigned long long* words = (unsigned long long*)(ws + WORD_OFF);
    int* counts  = (int*)(ws + CNT_OFF);
    int* total   = (int*)(ws + TOT_OFF);
    int* flatidx = (int*)(ws + IDX_OFF);

    // zero chunk counters each call (atomicAdd accumulates otherwise)
    hipMemsetAsync(ws + CNT_OFF, 0, NCHUNKS * 4, stream);

    mask_kernel<<<BATCH * 24 * 3, 256, 0, stream>>>(x, words, counts);
    scatter_kernel<<<NCHUNKS, 384, 0, stream>>>(words, counts, flatidx, total);
    fit_kernel<<<MAX_DET / 256, 256, 0, stream>>>(x, flatidx, total, out);
}

// Round 14
// 51.227 us; speedup vs baseline: 1.0761x; 1.0761x over previous
//
#include <hip/hip_runtime.h>
#include <hip/hip_bf16.h>
#include <cstdint>

// Problem constants
#define BATCH 16
#define HDIM 768
#define WDIM 768
#define HW (HDIM * WDIM)              // 589824
#define NPIX (BATCH * HW)             // 9437184
#define MAX_DET 393216
#define NWORDS (NPIX / 64)            // 147456
#define SCAT_BLOCKS 576               // NWORDS / 256
#define WPB 256                       // words per scatter/count block

// ws layout (byte offsets)
#define MASK_OFF 0u
#define CNT_OFF  1179648u
#define TOT_OFF  1187840u
#define IDX_OFF  1188096u

// Output layout (float elements)
#define SIGMA_BASE 0
#define POS_BASE   786432
#define HGT_BASE   1572864
#define GOOD_BASE  2359296

// mask tile geometry
#define TILE_C 256
#define TILE_R 32
#define LDS_C 264                     // cols cs*256-4 .. cs*256+259
#define LDS_R 36                      // rows r0-2 .. r0+33
#define VEC_PER_ROW 66                // 264/4
#define TOT_VEC (LDS_R * VEC_PER_ROW) // 2376

// ---------------------------------------------------------------
// ln(zf), f32 path: exact integer exponent split + hw v_log_f32 on
// the mantissa. abs err <= ~6e-7 (jax's own f32 jnp.log is similar).
// ---------------------------------------------------------------
__device__ __forceinline__ float fast_logf(float zf) {
    int ib = __float_as_int(zf);
    int e = ((ib >> 23) & 255) - 127;
    float m1 = __int_as_float((ib & 0x007fffff) | 0x3f800000);  // [1,2)
    float lg = __builtin_amdgcn_logf(m1);                       // log2(m1)
    return ((float)e + lg) * 0.69314718055994531f;
}

// Reciprocal via HW rcp_f32 seed + 2 f64 Newtons (~f64 rounding level).
__device__ __forceinline__ double fast_rcp(double d) {
    double r = (double)__builtin_amdgcn_rcpf((float)d);
    r = r * (2.0 - d * r);
    r = r * (2.0 - d * r);
    return r;
}

// ---------------------------------------------------------------
// Kernel 1: local-max via separable 5x5 max, LDS-tiled, float4.
// Word assembly via one LDS round-trip (no shfl chains).
// ---------------------------------------------------------------
__global__ __launch_bounds__(256) void mask_kernel(const float* __restrict__ x,
                                                   unsigned long long* __restrict__ mask) {
    __shared__ float lds[LDS_R * LDS_C];
    const int bid = blockIdx.x;             // 16 * 24 * 3 = 1152 blocks
    const int b   = bid / 72;
    const int rem = bid - b * 72;
    const int rt  = rem / 3;                // row tile 0..23
    const int cs  = rem - rt * 3;           // col strip 0..2
    const int r0  = rt * TILE_R;
    const int tid = threadIdx.x;
    const float* heat = x + (size_t)b * (2 * HW) + HW;   // channel 1

    // ---- stage thresholded tile (+halo) into LDS ----
    const int colbase = cs * TILE_C - 4;
    #pragma unroll
    for (int i = 0; i < 10; ++i) {
        int idx = i * 256 + tid;
        if (idx < TOT_VEC) {
            int lr = (unsigned)idx / VEC_PER_ROW;
            int q  = idx - lr * VEC_PER_ROW;
            int row = r0 - 2 + lr;
            int col = colbase + 4 * q;      // fully in-image or fully out
            float4 v = make_float4(0.f, 0.f, 0.f, 0.f);
            if (row >= 0 && row < HDIM && col >= 0 && col <= WDIM - 4) {
                v = *reinterpret_cast<const float4*>(heat + (size_t)row * WDIM + col);
            }
            float4 t;
            t.x = v.x > 0.5f ? v.x : 0.f;
            t.y = v.y > 0.5f ? v.y : 0.f;
            t.z = v.z > 0.5f ? v.z : 0.f;
            t.w = v.w > 0.5f ? v.w : 0.f;
            *reinterpret_cast<float4*>(&lds[lr * LDS_C + 4 * q]) = t;
        }
    }
    __syncthreads();

    // ---- compute: wave wv handles rows r0+wv*8 .. +7; lane owns 4 cols ----
    const int wv   = tid >> 6;
    const int lane = tid & 63;
    const int lrow0 = wv * 8;               // LDS row of first window row

    auto readrow = [&](int ldsrow, float* h5, float* hx, float* tc) {
        const float* p = &lds[ldsrow * LDS_C + 4 * lane];
        float4 a = *reinterpret_cast<const float4*>(p);
        float4 bb = *reinterpret_cast<const float4*>(p + 4);
        float4 cc = *reinterpret_cast<const float4*>(p + 8);
        float t2=a.z,t3=a.w,t4=bb.x,t5=bb.y,t6=bb.z,t7=bb.w,t8=cc.x,t9=cc.y;
        float pp0=fmaxf(t2,t3), pp1=fmaxf(t3,t4), pp2=fmaxf(t4,t5), pp3=fmaxf(t5,t6),
              pp4=fmaxf(t6,t7), pp5=fmaxf(t7,t8), pp6=fmaxf(t8,t9);
        h5[0]=fmaxf(fmaxf(pp0,pp2),t6);  hx[0]=fmaxf(pp0,pp3);  tc[0]=t4;
        h5[1]=fmaxf(fmaxf(pp1,pp3),t7);  hx[1]=fmaxf(pp1,pp4);  tc[1]=t5;
        h5[2]=fmaxf(fmaxf(pp2,pp4),t8);  hx[2]=fmaxf(pp2,pp5);  tc[2]=t6;
        h5[3]=fmaxf(fmaxf(pp3,pp5),t9);  hx[3]=fmaxf(pp3,pp6);  tc[3]=t7;
    };

    float h5r[5][4], hxr[5][4], tcr[5][4];
    #pragma unroll
    for (int j = 0; j < 4; ++j)
        readrow(lrow0 + j, h5r[j], hxr[j], tcr[j]);

    unsigned nibword = 0;                   // 8 nibbles, one per k
    #pragma unroll
    for (int k = 0; k < 8; ++k) {
        readrow(lrow0 + k + 4, h5r[(k+4)%5], hxr[(k+4)%5], tcr[(k+4)%5]);
        unsigned nib = 0;
        #pragma unroll
        for (int c = 0; c < 4; ++c) {
            float dil = fmaxf(fmaxf(h5r[k%5][c], h5r[(k+1)%5][c]),
                        fmaxf(hxr[(k+2)%5][c],
                        fmaxf(h5r[(k+3)%5][c], h5r[(k+4)%5][c])));
            if (tcr[(k+2)%5][c] > dil) nib |= (1u << c);
        }
        nibword |= nib << (4 * k);
    }

    // ---- assemble 64-bit words: one LDS round-trip, no shuffles ----
    __syncthreads();                        // all float reads done
    unsigned* lu = (unsigned*)lds;
    lu[tid] = nibword;
    __syncthreads();
    if (tid < 128) {
        const int wv2 = tid >> 5;           // 0..3 (wave group)
        const int k2  = (tid >> 2) & 7;     // 0..7 (row within group)
        const int wi  = tid & 3;            // 0..3 (word within row strip)
        const int s   = 4 * k2;
        const uint4* p = (const uint4*)&lu[wv2 * 64 + wi * 16];
        uint4 q0 = p[0], q1 = p[1], q2 = p[2], q3 = p[3];
        unsigned lo = 0, hi = 0;
        lo |= ((q0.x >> s) & 0xFu) << 0;   lo |= ((q0.y >> s) & 0xFu) << 4;
        lo |= ((q0.z >> s) & 0xFu) << 8;   lo |= ((q0.w >> s) & 0xFu) << 12;
        lo |= ((q1.x >> s) & 0xFu) << 16;  lo |= ((q1.y >> s) & 0xFu) << 20;
        lo |= ((q1.z >> s) & 0xFu) << 24;  lo |= ((q1.w >> s) & 0xFu) << 28;
        hi |= ((q2.x >> s) & 0xFu) << 0;   hi |= ((q2.y >> s) & 0xFu) << 4;
        hi |= ((q2.z >> s) & 0xFu) << 8;   hi |= ((q2.w >> s) & 0xFu) << 12;
        hi |= ((q3.x >> s) & 0xFu) << 16;  hi |= ((q3.y >> s) & 0xFu) << 20;
        hi |= ((q3.z >> s) & 0xFu) << 24;  hi |= ((q3.w >> s) & 0xFu) << 28;
        unsigned long long word = (unsigned long long)lo |
                                  ((unsigned long long)hi << 32);
        mask[b * (HW / 64) + (r0 + wv2 * 8 + k2) * 12 + cs * 4 + wi] = word;
    }
}

// ---------------------------------------------------------------
// Kernel 2: per-block popcount sums
// ---------------------------------------------------------------
__global__ __launch_bounds__(WPB) void count_kernel(const unsigned long long* __restrict__ mask,
                                                    int* __restrict__ counts) {
    __shared__ int s[WPB];
    int t = threadIdx.x;
    int w = blockIdx.x * WPB + t;
    s[t] = __popcll(mask[w]);
    __syncthreads();
    for (int off = WPB / 2; off > 0; off >>= 1) {
        if (t < off) s[t] += s[t + off];
        __syncthreads();
    }
    if (t == 0) counts[blockIdx.x] = s[0];
}

// ---------------------------------------------------------------
// Kernel 3 (merged scan+scatter): each block derives its own global
// offset from counts[0..bid); block 0 also writes *total.
// ---------------------------------------------------------------
__global__ __launch_bounds__(WPB) void scatter_kernel(const unsigned long long* __restrict__ mask,
                                                      const int* __restrict__ counts,
                                                      int* __restrict__ flat_idx,
                                                      int* __restrict__ total) {
    __shared__ int s[WPB];
    __shared__ int blockoff;
    const int t = threadIdx.x;
    const int bid = blockIdx.x;

    // exclusive prefix of counts over blocks [0, bid)
    int acc = 0;
    for (int i = t; i < bid; i += WPB) acc += counts[i];
    s[t] = acc;
    __syncthreads();
    for (int off = WPB / 2; off > 0; off >>= 1) {
        if (t < off) s[t] += s[t + off];
        __syncthreads();
    }
    if (t == 0) blockoff = s[0];
    __syncthreads();

    if (bid == 0) {
        int a2 = 0;
        for (int i = t; i < SCAT_BLOCKS; i += WPB) a2 += counts[i];
        s[t] = a2;
        __syncthreads();
        for (int off = WPB / 2; off > 0; off >>= 1) {
            if (t < off) s[t] += s[t + off];
            __syncthreads();
        }
        if (t == 0) *total = s[0];
        __syncthreads();
    }

    // in-block word-level exclusive prefix (Hillis-Steele)
    int w = bid * WPB + t;
    unsigned long long m = mask[w];
    int cnt = __popcll(m);
    s[t] = cnt;
    __syncthreads();
    for (int off = 1; off < WPB; off <<= 1) {
        int add = (t >= off) ? s[t - off] : 0;
        __syncthreads();
        s[t] += add;
        __syncthreads();
    }
    int base = blockoff + s[t] - cnt;
    int idx0 = w << 6;
    while (m) {
        int j = __builtin_ctzll(m);
        if (base < MAX_DET) flat_idx[base] = idx0 + j;
        ++base;
        m &= m - 1;
    }
}

// ---------------------------------------------------------------
// Kernel 4: fit — float4-pair gather -> f32 moments -> f64 GE.
// (Only delta vs r8: vectorized interior gather, 25 -> 10 VMEM.)
// ---------------------------------------------------------------
__global__ __launch_bounds__(256) void fit_kernel(const float* __restrict__ x,
                                                  const int* __restrict__ flat_idx,
                                                  const int* __restrict__ total,
                                                  float* __restrict__ out) {
    int n = blockIdx.x * 256 + threadIdx.x;   // 0..MAX_DET-1 (grid exact)
    int count = min(*total, MAX_DET);
    float sx = 0.f, sy = 0.f, p0 = 0.f, p1 = 0.f, h0 = 0.f, h1 = 0.f, goodf = 0.f;
    if (n < count) {
        int idx = flat_idx[n];
        int b = idx / HW;
        int rc = idx - b * HW;
        int r = rc / WDIM;
        int c = rc - r * WDIM;
        const float* heat = x + (size_t)b * (2 * HW) + HW;

        // gather 5x5 neighborhood (clipped) into registers
        float zv[25];
        if (c >= 2 && c <= WDIM - 3) {
            // fast path: 2 aligned float4 loads per row cover cols c-2..c+2
            const int a   = (c - 2) & ~3;
            const int ofs = (c - 2) & 3;
            #pragma unroll
            for (int dy = 0; dy < 5; ++dy) {
                int rr = min(max(r + dy - 2, 0), HDIM - 1);
                const float* hp = heat + (size_t)rr * WDIM + a;
                float4 u0 = *reinterpret_cast<const float4*>(hp);
                float4 u1 = *reinterpret_cast<const float4*>(hp + 4);
                float b0=u0.x, b1=u0.y, b2=u0.z, b3=u0.w;
                float b4=u1.x, b5=u1.y, b6=u1.z, b7=u1.w;
                float v0, v1, v2, v3, v4;
                if (ofs == 0)      { v0=b0; v1=b1; v2=b2; v3=b3; v4=b4; }
                else if (ofs == 1) { v0=b1; v1=b2; v2=b3; v3=b4; v4=b5; }
                else if (ofs == 2) { v0=b2; v1=b3; v2=b4; v3=b5; v4=b6; }
                else               { v0=b3; v1=b4; v2=b5; v3=b6; v4=b7; }
                zv[dy*5+0]=v0; zv[dy*5+1]=v1; zv[dy*5+2]=v2; zv[dy*5+3]=v3; zv[dy*5+4]=v4;
            }
        } else {
            #pragma unroll
            for (int dy = 0; dy < 5; ++dy) {
                int rr = min(max(r + dy - 2, 0), HDIM - 1);
                const float* hp = heat + (size_t)rr * WDIM;
                #pragma unroll
                for (int dx = 0; dx < 5; ++dx) {
                    int cc = min(max(c + dx - 2, 0), WDIM - 1);
                    zv[dy * 5 + dx] = hp[cc];
                }
            }
        }

        // Row-factorized moments in f32, weight w2 = z^4
        float M00=0,M10=0,M01=0,M20=0,M11=0,M02=0,M30=0,M21=0,M12=0,M03=0;
        float M40=0,M31=0,M22=0,M13=0,M04=0;
        float N0=0,N1=0,N2=0,N3=0,N4=0,N5=0;
        #pragma unroll
        for (int dy = -2; dy <= 2; ++dy) {
            float S0=0,S1=0,S2=0,S3=0,S4=0,T0=0,T1=0,T2=0;
            #pragma unroll
            for (int dx = -2; dx <= 2; ++dx) {
                float zf = fmaxf(zv[(dy + 2) * 5 + dx + 2], 1e-6f);
                float z2 = zf * zf;
                float w2 = z2 * z2;
                float wl = w2 * fast_logf(zf);
                const float X = (float)dx;         // literal after unroll
                S0 += w2; T0 += wl;
                if (dx != 0) {
                    S1 += w2 * X;
                    S2 += w2 * (X * X);
                    S3 += w2 * (X * X * X);
                    S4 += w2 * (X * X * X * X);
                    T1 += wl * X;
                    T2 += wl * (X * X);
                }
            }
            const float Y = (float)dy;             // literal after unroll
            M00 += S0; M10 += S1; M20 += S2; M30 += S3; M40 += S4;
            N0 += T0; N1 += T1; N2 += T2;
            if (dy != 0) {
                float Y2 = Y * Y, Y3 = Y2 * Y, Y4 = Y2 * Y2;
                M01 += S0 * Y;  M11 += S1 * Y;  M21 += S2 * Y;  M31 += S3 * Y;
                M02 += S0 * Y2; M12 += S1 * Y2; M22 += S2 * Y2;
                M03 += S0 * Y3; M13 += S1 * Y3;
                M04 += S0 * Y4;
                N3 += T0 * Y; N4 += T1 * Y; N5 += T0 * Y2;
            }
        }

        // Augmented 6x7 normal equations (f64), basis [1, x, x2, y, xy, y2]
        double A[6][7];
        A[0][0]=M00; A[0][1]=M10; A[0][2]=M20; A[0][3]=M01; A[0][4]=M11; A[0][5]=M02; A[0][6]=N0;
        A[1][0]=M10; A[1][1]=M20; A[1][2]=M30; A[1][3]=M11; A[1][4]=M21; A[1][5]=M12; A[1][6]=N1;
        A[2][0]=M20; A[2][1]=M30; A[2][2]=M40; A[2][3]=M21; A[2][4]=M31; A[2][5]=M22; A[2][6]=N2;
        A[3][0]=M01; A[3][1]=M11; A[3][2]=M21; A[3][3]=M02; A[3][4]=M12; A[3][5]=M03; A[3][6]=N3;
        A[4][0]=M11; A[4][1]=M21; A[4][2]=M31; A[4][3]=M12; A[4][4]=M22; A[4][5]=M13; A[4][6]=N4;
        A[5][0]=M02; A[5][1]=M12; A[5][2]=M22; A[5][3]=M03; A[5][4]=M13; A[5][5]=M04; A[5][6]=N5;

        // Gaussian elimination (no pivot; SPD), fully unrolled -> registers
        #pragma unroll
        for (int i = 0; i < 6; ++i) {
            double inv = fast_rcp(A[i][i]);
            #pragma unroll
            for (int j = i + 1; j < 7; ++j) A[i][j] *= inv;
            #pragma unroll
            for (int ii = i + 1; ii < 6; ++ii) {
                double f = A[ii][i];
                #pragma unroll
                for (int j = i + 1; j < 7; ++j) A[ii][j] -= f * A[i][j];
            }
        }
        double cv[6];
        #pragma unroll
        for (int i = 5; i >= 0; --i) {
            double v = A[i][6];
            #pragma unroll
            for (int j = i + 1; j < 6; ++j) v -= A[i][j] * cv[j];
            cv[i] = v;
        }

        double aqx = cv[2], aqy = cv[5];
        if (aqx < 0.0 && aqy < 0.0) {
            double sx2 = -0.5 * fast_rcp(aqx);
            double sy2 = -0.5 * fast_rcp(aqy);
            sx2 = fmin(sx2, 1e300);
            sy2 = fmin(sy2, 1e300);
            double sigx = sqrt(sx2), sigy = sqrt(sy2);
            double mux = cv[1] * sx2, muy = cv[3] * sy2;
            sx = (float)sigx;
            sy = (float)sigy;
            p0 = (float)((double)r + muy);   // pos[:,0] = r + mu_y
            p1 = (float)((double)c + mux);   // pos[:,1] = c + mu_x
            // height threshold is inf (observed): f32 exp2 path, clamped finite.
            float a0 = (float)((cv[0] + 0.5 * cv[1] * cv[1] * sx2) * 1.4426950408889634);
            float a1 = (float)((cv[4] + 0.5 * cv[3] * cv[3] * sy2) * 1.4426950408889634);
            a0 = fminf(a0, 126.0f);          // exp2(126)=8.5e37: finite in f32
            a1 = fminf(a1, 126.0f);
            h0 = exp2f(a0);
            h1 = exp2f(a1);
            goodf = 1.0f;
        }
    }
    out[SIGMA_BASE + 2 * n]     = sx;
    out[SIGMA_BASE + 2 * n + 1] = sy;
    out[POS_BASE + 2 * n]       = p0;
    out[POS_BASE + 2 * n + 1]   = p1;
    out[HGT_BASE + 2 * n]       = h0;
    out[HGT_BASE + 2 * n + 1]   = h1;
    out[GOOD_BASE + n]          = goodf;
}

extern "C" void kernel_launch(void* const* d_in, const int* in_sizes, int n_in,
                              void* d_out, int out_size, void* d_ws, size_t ws_size,
                              hipStream_t stream) {
    const float* x = (const float*)d_in[0];
    float* out = (float*)d_out;
    char* ws = (char*)d_ws;

    unsigned long long* mask = (unsigned long long*)(ws + MASK_OFF);
    int* counts  = (int*)(ws + CNT_OFF);
    int* total   = (int*)(ws + TOT_OFF);
    int* flatidx = (int*)(ws + IDX_OFF);

    mask_kernel<<<BATCH * 24 * 3, 256, 0, stream>>>(x, mask);
    count_kernel<<<SCAT_BLOCKS, WPB, 0, stream>>>(mask, counts);
    scatter_kernel<<<SCAT_BLOCKS, WPB, 0, stream>>>(mask, counts, flatidx, total);
    fit_kernel<<<MAX_DET / 256, 256, 0, stream>>>(x, flatidx, total, out);
}

// Round 15
// 45.775 us; speedup vs baseline: 1.2043x; 1.1191x over previous
//
#include <hip/hip_runtime.h>
#include <hip/hip_bf16.h>
#include <cstdint>

// Problem constants
#define BATCH 16
#define HDIM 768
#define WDIM 768
#define HW (HDIM * WDIM)              // 589824
#define NPIX (BATCH * HW)             // 9437184
#define MAX_DET 393216
#define NWORDS (NPIX / 64)            // 147456
#define SCAT_BLOCKS 576               // NWORDS / 256
#define WPB 256                       // words per scatter/count block

// ws layout (byte offsets)
#define MASK_OFF 0u
#define CNT_OFF  1179648u
#define TOT_OFF  1187840u
#define IDX_OFF  1188096u

// Output layout (float elements)
#define SIGMA_BASE 0
#define POS_BASE   786432
#define HGT_BASE   1572864
#define GOOD_BASE  2359296

// mask tile geometry
#define TILE_C 256
#define TILE_R 32
#define LDS_C 264                     // cols cs*256-4 .. cs*256+259
#define LDS_R 36                      // rows r0-2 .. r0+33
#define VEC_PER_ROW 66                // 264/4
#define TOT_VEC (LDS_R * VEC_PER_ROW) // 2376

// ---------------------------------------------------------------
// ln(zf), f32 path: exact integer exponent split + hw v_log_f32 on
// the mantissa. abs err <= ~6e-7 (jax's own f32 jnp.log is similar).
// ---------------------------------------------------------------
__device__ __forceinline__ float fast_logf(float zf) {
    int ib = __float_as_int(zf);
    int e = ((ib >> 23) & 255) - 127;
    float m1 = __int_as_float((ib & 0x007fffff) | 0x3f800000);  // [1,2)
    float lg = __builtin_amdgcn_logf(m1);                       // log2(m1)
    return ((float)e + lg) * 0.69314718055994531f;
}

// Reciprocal via HW rcp_f32 seed + 2 f64 Newtons (~f64 rounding level).
__device__ __forceinline__ double fast_rcp(double d) {
    double r = (double)__builtin_amdgcn_rcpf((float)d);
    r = r * (2.0 - d * r);
    r = r * (2.0 - d * r);
    return r;
}

// ---------------------------------------------------------------
// Kernel 1: local-max via separable 5x5 max, LDS-tiled, float4.
// Word assembly via one LDS round-trip (no shfl chains).
// ---------------------------------------------------------------
__global__ __launch_bounds__(256) void mask_kernel(const float* __restrict__ x,
                                                   unsigned long long* __restrict__ mask) {
    __shared__ float lds[LDS_R * LDS_C];
    const int bid = blockIdx.x;             // 16 * 24 * 3 = 1152 blocks
    const int b   = bid / 72;
    const int rem = bid - b * 72;
    const int rt  = rem / 3;                // row tile 0..23
    const int cs  = rem - rt * 3;           // col strip 0..2
    const int r0  = rt * TILE_R;
    const int tid = threadIdx.x;
    const float* heat = x + (size_t)b * (2 * HW) + HW;   // channel 1

    // ---- stage thresholded tile (+halo) into LDS ----
    const int colbase = cs * TILE_C - 4;
    #pragma unroll
    for (int i = 0; i < 10; ++i) {
        int idx = i * 256 + tid;
        if (idx < TOT_VEC) {
            int lr = (unsigned)idx / VEC_PER_ROW;
            int q  = idx - lr * VEC_PER_ROW;
            int row = r0 - 2 + lr;
            int col = colbase + 4 * q;      // fully in-image or fully out
            float4 v = make_float4(0.f, 0.f, 0.f, 0.f);
            if (row >= 0 && row < HDIM && col >= 0 && col <= WDIM - 4) {
                v = *reinterpret_cast<const float4*>(heat + (size_t)row * WDIM + col);
            }
            float4 t;
            t.x = v.x > 0.5f ? v.x : 0.f;
            t.y = v.y > 0.5f ? v.y : 0.f;
            t.z = v.z > 0.5f ? v.z : 0.f;
            t.w = v.w > 0.5f ? v.w : 0.f;
            *reinterpret_cast<float4*>(&lds[lr * LDS_C + 4 * q]) = t;
        }
    }
    __syncthreads();

    // ---- compute: wave wv handles rows r0+wv*8 .. +7; lane owns 4 cols ----
    const int wv   = tid >> 6;
    const int lane = tid & 63;
    const int lrow0 = wv * 8;               // LDS row of first window row

    auto readrow = [&](int ldsrow, float* h5, float* hx, float* tc) {
        const float* p = &lds[ldsrow * LDS_C + 4 * lane];
        float4 a = *reinterpret_cast<const float4*>(p);
        float4 bb = *reinterpret_cast<const float4*>(p + 4);
        float4 cc = *reinterpret_cast<const float4*>(p + 8);
        float t2=a.z,t3=a.w,t4=bb.x,t5=bb.y,t6=bb.z,t7=bb.w,t8=cc.x,t9=cc.y;
        float pp0=fmaxf(t2,t3), pp1=fmaxf(t3,t4), pp2=fmaxf(t4,t5), pp3=fmaxf(t5,t6),
              pp4=fmaxf(t6,t7), pp5=fmaxf(t7,t8), pp6=fmaxf(t8,t9);
        h5[0]=fmaxf(fmaxf(pp0,pp2),t6);  hx[0]=fmaxf(pp0,pp3);  tc[0]=t4;
        h5[1]=fmaxf(fmaxf(pp1,pp3),t7);  hx[1]=fmaxf(pp1,pp4);  tc[1]=t5;
        h5[2]=fmaxf(fmaxf(pp2,pp4),t8);  hx[2]=fmaxf(pp2,pp5);  tc[2]=t6;
        h5[3]=fmaxf(fmaxf(pp3,pp5),t9);  hx[3]=fmaxf(pp3,pp6);  tc[3]=t7;
    };

    float h5r[5][4], hxr[5][4], tcr[5][4];
    #pragma unroll
    for (int j = 0; j < 4; ++j)
        readrow(lrow0 + j, h5r[j], hxr[j], tcr[j]);

    unsigned nibword = 0;                   // 8 nibbles, one per k
    #pragma unroll
    for (int k = 0; k < 8; ++k) {
        readrow(lrow0 + k + 4, h5r[(k+4)%5], hxr[(k+4)%5], tcr[(k+4)%5]);
        unsigned nib = 0;
        #pragma unroll
        for (int c = 0; c < 4; ++c) {
            float dil = fmaxf(fmaxf(h5r[k%5][c], h5r[(k+1)%5][c]),
                        fmaxf(hxr[(k+2)%5][c],
                        fmaxf(h5r[(k+3)%5][c], h5r[(k+4)%5][c])));
            if (tcr[(k+2)%5][c] > dil) nib |= (1u << c);
        }
        nibword |= nib << (4 * k);
    }

    // ---- assemble 64-bit words: one LDS round-trip, no shuffles ----
    __syncthreads();                        // all float reads done
    unsigned* lu = (unsigned*)lds;
    lu[tid] = nibword;
    __syncthreads();
    if (tid < 128) {
        const int wv2 = tid >> 5;           // 0..3 (wave group)
        const int k2  = (tid >> 2) & 7;     // 0..7 (row within group)
        const int wi  = tid & 3;            // 0..3 (word within row strip)
        const int s   = 4 * k2;
        const uint4* p = (const uint4*)&lu[wv2 * 64 + wi * 16];
        uint4 q0 = p[0], q1 = p[1], q2 = p[2], q3 = p[3];
        unsigned lo = 0, hi = 0;
        lo |= ((q0.x >> s) & 0xFu) << 0;   lo |= ((q0.y >> s) & 0xFu) << 4;
        lo |= ((q0.z >> s) & 0xFu) << 8;   lo |= ((q0.w >> s) & 0xFu) << 12;
        lo |= ((q1.x >> s) & 0xFu) << 16;  lo |= ((q1.y >> s) & 0xFu) << 20;
        lo |= ((q1.z >> s) & 0xFu) << 24;  lo |= ((q1.w >> s) & 0xFu) << 28;
        hi |= ((q2.x >> s) & 0xFu) << 0;   hi |= ((q2.y >> s) & 0xFu) << 4;
        hi |= ((q2.z >> s) & 0xFu) << 8;   hi |= ((q2.w >> s) & 0xFu) << 12;
        hi |= ((q3.x >> s) & 0xFu) << 16;  hi |= ((q3.y >> s) & 0xFu) << 20;
        hi |= ((q3.z >> s) & 0xFu) << 24;  hi |= ((q3.w >> s) & 0xFu) << 28;
        unsigned long long word = (unsigned long long)lo |
                                  ((unsigned long long)hi << 32);
        mask[b * (HW / 64) + (r0 + wv2 * 8 + k2) * 12 + cs * 4 + wi] = word;
    }
}

// ---------------------------------------------------------------
// Kernel 2: per-block popcount sums
// ---------------------------------------------------------------
__global__ __launch_bounds__(WPB) void count_kernel(const unsigned long long* __restrict__ mask,
                                                    int* __restrict__ counts) {
    __shared__ int s[WPB];
    int t = threadIdx.x;
    int w = blockIdx.x * WPB + t;
    s[t] = __popcll(mask[w]);
    __syncthreads();
    for (int off = WPB / 2; off > 0; off >>= 1) {
        if (t < off) s[t] += s[t + off];
        __syncthreads();
    }
    if (t == 0) counts[blockIdx.x] = s[0];
}

// ---------------------------------------------------------------
// Kernel 3 (merged scan+scatter): each block derives its own global
// offset from counts[0..bid); block 0 also writes *total.
// ---------------------------------------------------------------
__global__ __launch_bounds__(WPB) void scatter_kernel(const unsigned long long* __restrict__ mask,
                                                      const int* __restrict__ counts,
                                                      int* __restrict__ flat_idx,
                                                      int* __restrict__ total) {
    __shared__ int s[WPB];
    __shared__ int blockoff;
    const int t = threadIdx.x;
    const int bid = blockIdx.x;

    // exclusive prefix of counts over blocks [0, bid)
    int acc = 0;
    for (int i = t; i < bid; i += WPB) acc += counts[i];
    s[t] = acc;
    __syncthreads();
    for (int off = WPB / 2; off > 0; off >>= 1) {
        if (t < off) s[t] += s[t + off];
        __syncthreads();
    }
    if (t == 0) blockoff = s[0];
    __syncthreads();

    if (bid == 0) {
        int a2 = 0;
        for (int i = t; i < SCAT_BLOCKS; i += WPB) a2 += counts[i];
        s[t] = a2;
        __syncthreads();
        for (int off = WPB / 2; off > 0; off >>= 1) {
            if (t < off) s[t] += s[t + off];
            __syncthreads();
        }
        if (t == 0) *total = s[0];
        __syncthreads();
    }

    // in-block word-level exclusive prefix (Hillis-Steele)
    int w = bid * WPB + t;
    unsigned long long m = mask[w];
    int cnt = __popcll(m);
    s[t] = cnt;
    __syncthreads();
    for (int off = 1; off < WPB; off <<= 1) {
        int add = (t >= off) ? s[t - off] : 0;
        __syncthreads();
        s[t] += add;
        __syncthreads();
    }
    int base = blockoff + s[t] - cnt;
    int idx0 = w << 6;
    while (m) {
        int j = __builtin_ctzll(m);
        if (base < MAX_DET) flat_idx[base] = idx0 + j;
        ++base;
        m &= m - 1;
    }
}

// ---------------------------------------------------------------
// Kernel 4: per-detection weighted quadratic fit.
// f32 moment phase with INLINE scalar gather (r8-proven: compiler
// interleaves the 25 independent loads with moment FMAs at 48 VGPR;
// batched/vectorized gathers measured SLOWER) -> f64 no-pivot GE.
// ---------------------------------------------------------------
__global__ __launch_bounds__(256) void fit_kernel(const float* __restrict__ x,
                                                  const int* __restrict__ flat_idx,
                                                  const int* __restrict__ total,
                                                  float* __restrict__ out) {
    int n = blockIdx.x * 256 + threadIdx.x;   // 0..MAX_DET-1 (grid exact)
    int count = *total;
    float sx = 0.f, sy = 0.f, p0 = 0.f, p1 = 0.f, h0 = 0.f, h1 = 0.f, goodf = 0.f;
    if (n < count) {
        int idx = flat_idx[n];
        int b = idx / HW;
        int rc = idx - b * HW;
        int r = rc / WDIM;
        int c = rc - r * WDIM;
        const float* heat = x + (size_t)b * (2 * HW) + HW;

        // Row-factorized moments in f32, weight w2 = z^4
        float M00=0,M10=0,M01=0,M20=0,M11=0,M02=0,M30=0,M21=0,M12=0,M03=0;
        float M40=0,M31=0,M22=0,M13=0,M04=0;
        float N0=0,N1=0,N2=0,N3=0,N4=0,N5=0;
        #pragma unroll
        for (int dy = -2; dy <= 2; ++dy) {
            int rr = min(max(r + dy, 0), HDIM - 1);
            const float* hp = heat + (size_t)rr * WDIM;
            float S0=0,S1=0,S2=0,S3=0,S4=0,T0=0,T1=0,T2=0;
            #pragma unroll
            for (int dx = -2; dx <= 2; ++dx) {
                int cc = min(max(c + dx, 0), WDIM - 1);
                float zf = fmaxf(hp[cc], 1e-6f);
                float z2 = zf * zf;
                float w2 = z2 * z2;
                float wl = w2 * fast_logf(zf);
                const float X = (float)dx;         // literal after unroll
                S0 += w2; T0 += wl;
                if (dx != 0) {
                    S1 += w2 * X;
                    S2 += w2 * (X * X);
                    S3 += w2 * (X * X * X);
                    S4 += w2 * (X * X * X * X);
                    T1 += wl * X;
                    T2 += wl * (X * X);
                }
            }
            const float Y = (float)dy;             // literal after unroll
            M00 += S0; M10 += S1; M20 += S2; M30 += S3; M40 += S4;
            N0 += T0; N1 += T1; N2 += T2;
            if (dy != 0) {
                float Y2 = Y * Y, Y3 = Y2 * Y, Y4 = Y2 * Y2;
                M01 += S0 * Y;  M11 += S1 * Y;  M21 += S2 * Y;  M31 += S3 * Y;
                M02 += S0 * Y2; M12 += S1 * Y2; M22 += S2 * Y2;
                M03 += S0 * Y3; M13 += S1 * Y3;
                M04 += S0 * Y4;
                N3 += T0 * Y; N4 += T1 * Y; N5 += T0 * Y2;
            }
        }

        // Augmented 6x7 normal equations (f64), basis [1, x, x2, y, xy, y2]
        double A[6][7];
        A[0][0]=M00; A[0][1]=M10; A[0][2]=M20; A[0][3]=M01; A[0][4]=M11; A[0][5]=M02; A[0][6]=N0;
        A[1][0]=M10; A[1][1]=M20; A[1][2]=M30; A[1][3]=M11; A[1][4]=M21; A[1][5]=M12; A[1][6]=N1;
        A[2][0]=M20; A[2][1]=M30; A[2][2]=M40; A[2][3]=M21; A[2][4]=M31; A[2][5]=M22; A[2][6]=N2;
        A[3][0]=M01; A[3][1]=M11; A[3][2]=M21; A[3][3]=M02; A[3][4]=M12; A[3][5]=M03; A[3][6]=N3;
        A[4][0]=M11; A[4][1]=M21; A[4][2]=M31; A[4][3]=M12; A[4][4]=M22; A[4][5]=M13; A[4][6]=N4;
        A[5][0]=M02; A[5][1]=M12; A[5][2]=M22; A[5][3]=M03; A[5][4]=M13; A[5][5]=M04; A[5][6]=N5;

        // Gaussian elimination (no pivot; SPD), fully unrolled -> registers
        #pragma unroll
        for (int i = 0; i < 6; ++i) {
            double inv = fast_rcp(A[i][i]);
            #pragma unroll
            for (int j = i + 1; j < 7; ++j) A[i][j] *= inv;
            #pragma unroll
            for (int ii = i + 1; ii < 6; ++ii) {
                double f = A[ii][i];
                #pragma unroll
                for (int j = i + 1; j < 7; ++j) A[ii][j] -= f * A[i][j];
            }
        }
        double cv[6];
        #pragma unroll
        for (int i = 5; i >= 0; --i) {
            double v = A[i][6];
            #pragma unroll
            for (int j = i + 1; j < 6; ++j) v -= A[i][j] * cv[j];
            cv[i] = v;
        }

        double aqx = cv[2], aqy = cv[5];
        if (aqx < 0.0 && aqy < 0.0) {
            double sx2 = -0.5 * fast_rcp(aqx);
            double sy2 = -0.5 * fast_rcp(aqy);
            sx2 = fmin(sx2, 1e300);
            sy2 = fmin(sy2, 1e300);
            double sigx = sqrt(sx2), sigy = sqrt(sy2);
            double mux = cv[1] * sx2, muy = cv[3] * sy2;
            sx = (float)sigx;
            sy = (float)sigy;
            p0 = (float)((double)r + muy);   // pos[:,0] = r + mu_y
            p1 = (float)((double)c + mux);   // pos[:,1] = c + mu_x
            // height threshold is inf (observed): f32 exp2 path, clamped finite.
            float a0 = (float)((cv[0] + 0.5 * cv[1] * cv[1] * sx2) * 1.4426950408889634);
            float a1 = (float)((cv[4] + 0.5 * cv[3] * cv[3] * sy2) * 1.4426950408889634);
            a0 = fminf(a0, 126.0f);          // exp2(126)=8.5e37: finite in f32
            a1 = fminf(a1, 126.0f);
            h0 = exp2f(a0);
            h1 = exp2f(a1);
            goodf = 1.0f;
        }
    }
    out[SIGMA_BASE + 2 * n]     = sx;
    out[SIGMA_BASE + 2 * n + 1] = sy;
    out[POS_BASE + 2 * n]       = p0;
    out[POS_BASE + 2 * n + 1]   = p1;
    out[HGT_BASE + 2 * n]       = h0;
    out[HGT_BASE + 2 * n + 1]   = h1;
    out[GOOD_BASE + n]          = goodf;
}

extern "C" void kernel_launch(void* const* d_in, const int* in_sizes, int n_in,
                              void* d_out, int out_size, void* d_ws, size_t ws_size,
                              hipStream_t stream) {
    const float* x = (const float*)d_in[0];
    float* out = (float*)d_out;
    char* ws = (char*)d_ws;

    unsigned long long* mask = (unsigned long long*)(ws + MASK_OFF);
    int* counts  = (int*)(ws + CNT_OFF);
    int* total   = (int*)(ws + TOT_OFF);
    int* flatidx = (int*)(ws + IDX_OFF);

    mask_kernel<<<BATCH * 24 * 3, 256, 0, stream>>>(x, mask);
    count_kernel<<<SCAT_BLOCKS, WPB, 0, stream>>>(mask, counts);
    scatter_kernel<<<SCAT_BLOCKS, WPB, 0, stream>>>(mask, counts, flatidx, total);
    fit_kernel<<<MAX_DET / 256, 256, 0, stream>>>(x, flatidx, total, out);
}